// Round 18
// baseline (236.620 us; speedup 1.0000x reference)
//
#include <hip/hip_runtime.h>
#include <hip/hip_bf16.h>

#define TOKENS 2048
#define DIM    1024
#define FDIM   1408
#define NEXP   16
#define NK     (TOKENS * 2)
#define CAP    320
#define RPAD   384          // padded rows per expert

typedef __attribute__((ext_vector_type(4))) float f32x4;
typedef __attribute__((ext_vector_type(2))) float f32x2;
typedef __attribute__((ext_vector_type(8))) short s16x8;
typedef __attribute__((ext_vector_type(4))) short s16x4;

__device__ __forceinline__ short f2bf(float f) {
    unsigned int u = __float_as_uint(f);
    u += 0x7FFFu + ((u >> 16) & 1u);   // RNE
    return (short)(u >> 16);
}
__device__ __forceinline__ float bf2f(short s) {
    return __uint_as_float(((unsigned int)(unsigned short)s) << 16);
}
__device__ __forceinline__ unsigned int f2bf_pk(float lo, float hi) {
    union { __hip_bfloat162 h; unsigned int u; } c;
    c.h = __float22bfloat162_rn(make_float2(lo, hi));   // RNE == f2bf bits
    return c.u;
}

#define GLDS16(gp, lp) __builtin_amdgcn_global_load_lds(                     \
    (const __attribute__((address_space(1))) unsigned int*)(gp),             \
    (__attribute__((address_space(3))) unsigned int*)(lp), 16, 0, 0)

// ---------------- arg structs ----------------
struct GSegF {                       // fused-conversion GEMM (fp32 B), BM=256
    const short* A; long aStride; int aRpad;
    const float* B0; const float* B1; long bStride;
    short* Out; long oStride; int oRpad;
    const int* cnt; int Mb, Nb, N, K, rlim, nblocks;
};
struct GSegB {                       // GLDS bf16-B GEMM (BM=64, BN=256)
    const short* A; long aStride; int aRpad;
    const short* B0; long bStride;
    short* Out; long oStride;
    const int* cnt; int Mb, Nb, N, K, nblocks;
};
struct WSeg { const float* in; short* out; int K, N, mats, nblocks; };

// ------- Weight chunk-reorder: fp32 [K][N] -> bf16 [K/8][N][8] --------------
// 512-thread version (rides in the gateup launch): thread owns 2 adjacent
// cols; 512 threads cover 1024 cols per iteration.
__device__ void wchunk_dev(const WSeg& W, int bid)
{
    const int spm = W.K >> 3;
    const int mat = bid / spm, s = bid % spm;
    const float* in  = W.in  + (size_t)mat * W.K * W.N + (size_t)s * 8 * W.N;
    short* out = W.out + (size_t)mat * W.K * W.N + (size_t)s * W.N * 8;
    const int t = threadIdx.x;
    for (int n = 2 * t; n < W.N; n += 1024) {
        const float* src = in + n;
        s16x8 o0, o1;
#pragma unroll
        for (int j = 0; j < 8; j++) {
            float2 v = *(const float2*)(src + (size_t)j * W.N);
            o0[j] = f2bf(v.x);
            o1[j] = f2bf(v.y);
        }
        *(s16x8*)(out + (size_t)n * 8)     = o0;
        *(s16x8*)(out + (size_t)n * 8 + 8) = o1;
    }
}

// -------- Router device -----------------------------------------------------
__device__ void router_dev(const float* __restrict__ x, const float* __restrict__ rw,
                           const float* __restrict__ rb, int* __restrict__ idx_flat,
                           float* __restrict__ vals_flat, int bid)
{
    __shared__ float lg[16][17];
    const int t  = threadIdx.x;
    const int tl = t >> 4;
    const int e  = t & 15;
    const int token = bid * 16 + tl;
    const float* xr = x + (size_t)token * DIM;

    float acc = 0.f;
    for (int d4 = 0; d4 < DIM / 4; d4++) {
        float4 xv = *(const float4*)(xr + d4 * 4);
        acc += xv.x * rw[(d4 * 4 + 0) * NEXP + e];
        acc += xv.y * rw[(d4 * 4 + 1) * NEXP + e];
        acc += xv.z * rw[(d4 * 4 + 2) * NEXP + e];
        acc += xv.w * rw[(d4 * 4 + 3) * NEXP + e];
    }
    lg[tl][e] = acc + rb[e];
    __syncthreads();

    if (t < 16) {
        float l[16];
#pragma unroll
        for (int j = 0; j < 16; j++) l[j] = lg[t][j];
        float m = l[0];
#pragma unroll
        for (int j = 1; j < 16; j++) m = fmaxf(m, l[j]);
        float p[16], den = 0.f;
#pragma unroll
        for (int j = 0; j < 16; j++) { p[j] = __expf(l[j] - m); den += p[j]; }
        int i1 = -1; float b1 = -1e30f;
#pragma unroll
        for (int j = 0; j < 16; j++) if (p[j] > b1) { b1 = p[j]; i1 = j; }
        int i2 = -1; float b2 = -1e30f;
#pragma unroll
        for (int j = 0; j < 16; j++) if (j != i1 && p[j] > b2) { b2 = p[j]; i2 = j; }
        float v1 = b1 / den, v2 = b2 / den;
        float s = v1 + v2 + 1e-9f;
        int tok = bid * 16 + t;
        idx_flat[tok * 2 + 0] = i1;
        idx_flat[tok * 2 + 1] = i2;
        vals_flat[tok * 2 + 0] = v1 / s;
        vals_flat[tok * 2 + 1] = v2 / s;
    }
}

// -------- xconv device: x -> bf16 chunk [DIM/8][TOKENS][8]; 2 tokens/block --
__device__ void xconv_dev(const float* __restrict__ x, short* __restrict__ xb, int bid)
{
    const int token = bid * 2 + (threadIdx.x >> 7);
    const int c = threadIdx.x & 127;
    const float* src = x + (size_t)token * DIM + c * 8;
    float4 v0 = *(const float4*)(src);
    float4 v1 = *(const float4*)(src + 4);
    s16x8 o;
    o[0] = f2bf(v0.x); o[1] = f2bf(v0.y); o[2] = f2bf(v0.z); o[3] = f2bf(v0.w);
    o[4] = f2bf(v1.x); o[5] = f2bf(v1.y); o[6] = f2bf(v1.z); o[7] = f2bf(v1.w);
    *(s16x8*)(xb + (size_t)c * (TOKENS * 8) + (size_t)token * 8) = o;
}

// ---- K1: router + xconv ----------------------------------------------------
__global__ __launch_bounds__(256) void rx_kernel(
    const float* __restrict__ x, const float* __restrict__ rw,
    const float* __restrict__ rb, int* __restrict__ idx_flat,
    float* __restrict__ vals, short* __restrict__ xb)
{
    int bid = blockIdx.x;
    if (bid < TOKENS / 16) { router_dev(x, rw, rb, idx_flat, vals, bid); return; }
    xconv_dev(x, xb, bid - TOKENS / 16);
}

// ------------- Sequential position scan (1 wave, ballot-based) --------------
__global__ void scan_kernel(const int* __restrict__ idx_flat,
                            const float* __restrict__ vals,
                            int* __restrict__ dst, float* __restrict__ wgt,
                            int* __restrict__ cnt)
{
    const int lane = threadIdx.x;   // 64 threads
    int base[16];
#pragma unroll
    for (int e = 0; e < 16; e++) base[e] = 0;

    for (int c = 0; c < NK / 64; c++) {
        int i = c * 64 + lane;
        int e = idx_flat[i];
        unsigned long long m[16];
#pragma unroll
        for (int ee = 0; ee < 16; ee++) m[ee] = __ballot(e == ee);
        unsigned long long mym = 0ULL; int myb = 0;
#pragma unroll
        for (int ee = 0; ee < 16; ee++) {
            bool sel = (e == ee);
            mym = sel ? m[ee] : mym;
            myb = sel ? base[ee] : myb;
        }
        int pos = myb + (int)__popcll(mym & ((1ULL << lane) - 1ULL));
        bool within = pos < CAP;
        dst[i] = within ? (e * RPAD + pos) : -1;
        wgt[i] = within ? vals[i] : 0.f;
#pragma unroll
        for (int ee = 0; ee < 16; ee++) base[ee] += (int)__popcll(m[ee]);
    }
    if (lane < 16) cnt[lane] = base[lane] < CAP ? base[lane] : CAP;
}

// ---- Scatter: token into expert buffer chunk [K/8][RPAD][8]; 2/block -------
__global__ __launch_bounds__(256) void scatter_kernel(
    const float* __restrict__ x, const int* __restrict__ dst,
    const int* __restrict__ idx_flat, short* __restrict__ ex)
{
    const int i = blockIdx.x * 2 + (threadIdx.x >> 7);
    const int d0 = dst[i];
    if (d0 < 0) return;
    const int e = idx_flat[i];
    const int pos = d0 - e * RPAD;
    const int token = i >> 1;
    const int c = threadIdx.x & 127;
    const float* src = x + (size_t)token * DIM + c * 8;
    float4 v0 = *(const float4*)(src);
    float4 v1 = *(const float4*)(src + 4);
    s16x8 o;
    o[0] = f2bf(v0.x); o[1] = f2bf(v0.y); o[2] = f2bf(v0.z); o[3] = f2bf(v0.w);
    o[4] = f2bf(v1.x); o[5] = f2bf(v1.y); o[6] = f2bf(v1.z); o[7] = f2bf(v1.w);
    *(s16x8*)(ex + (size_t)e * (DIM * RPAD) + (size_t)c * (RPAD * 8) +
              (size_t)pos * 8) = o;
}

// ---------------- Fused-conversion GEMM, BM=256, NMAT=2, 512 threads --------
// r18: bigger M-tile cuts B fp32 re-reads (the binding constraint per the
// delivered-bandwidth model): expert Mb_eff 2.4 -> ~1.25, shared Mb 16 -> 8.
// 8 waves (4x2), wave tile 64x64 per mat; acc 128 regs + staging ~90 -> fits
// (512,2) = 8 waves/CU (1 block).
// A: bf16 chunk [K/8][aRpad][8] via 2 GLDS16/thread/Kstep.
// B: fp32 [K][N] staged global->reg->pk-cvt->ds_write (4 f32x4/thread:
//    4 cols x 4 k-rows); B LDS cols XOR-swizzled colS = col^((col>>3)&7).
// vmcnt ledger: per iter issues B(4)+A(2); top-of-iter outstanding =
// A(ks)2 + B(ks+1)4 + A(ks+1)2 = 8 -> vmcnt(6) retires A(ks).
// Expert block m0=256 covers rows 256..511: A-reads overrun into ws slack
// (harmless); epilogue stores guarded row < rlim (=RPAD) so the next
// expert's output is never touched.
__device__ void gemm_fused256_dev(const GSegF& S, int bid)
{
    constexpr int BUFS = 8192 + 8192;   // shorts: A 16KB + B 2x8KB = 32KB/buf
    __shared__ short lds[2 * BUFS];

    const int cpx = S.nblocks >> 3;     // XCD swizzle, m fastest (nblocks%8==0)
    const int lid = (bid & 7) * cpx + (bid >> 3);
    const int mb  = lid % S.Mb;
    const int t1  = lid / S.Mb;
    const int nb  = t1 % S.Nb;
    const int g   = t1 / S.Nb;
    const int m0 = mb * 256, n0 = nb * 128;
    if (S.cnt != nullptr && m0 >= S.cnt[g]) return;

    const int tid = threadIdx.x, lane = tid & 63, w = tid >> 6;   // w 0..7
    const int wr = w >> 1, wc = w & 1, ln = lane & 15, kg = lane >> 4;
    const int N = S.N, K = S.K;

    const short* Ag  = S.A  + (size_t)g * S.aStride + (size_t)m0 * 8;
    const float* Bg0 = S.B0 + (size_t)g * S.bStride + n0;
    const float* Bg1 = S.B1 + (size_t)g * S.bStride + n0;

    const size_t aR8 = (size_t)S.aRpad * 8;

    // A staging: 8192 shorts/step; thread covers [tid*8] and [4096 + tid*8]
    const short* aS0 = Ag + (size_t)(tid >> 8) * aR8 + (size_t)(tid & 255) * 8;
    const short* aS1 = Ag + (size_t)(2 + (tid >> 8)) * aR8 + (size_t)(tid & 255) * 8;
    const int dA0 = w * 512, dA1 = 4096 + w * 512;

    // B staging: mat = tid>>8; within mat: 32 col-groups x 8 krow-groups
    const int matid = tid >> 8, r = tid & 255;
    const int c4 = (r & 31) * 4;        // col base (4 cols)
    const int g4 = r >> 5;              // k-row group (4 rows), 0..7
    const float* bSrc = (matid ? Bg1 : Bg0) + (size_t)g4 * 4 * N + c4;
    const int bKg  = g4 >> 1;           // kg (8-row unit)
    const int bOff = (g4 & 1) * 4;      // short offset within unit
    const int rB = 8192 + matid * 4096 + bKg * 1024;

    f32x4 bq[4];

    auto LOADB = [&](int ks) {
        const float* p = bSrc + (size_t)ks * 32 * N;
#pragma unroll
        for (int j = 0; j < 4; j++) bq[j] = *(const f32x4*)(p + (size_t)j * N);
    };
    auto STGA = [&](int buf, int ks) {
        const size_t ka = (size_t)ks * 4 * aR8;
        short* base = lds + buf * BUFS;
        GLDS16(aS0 + ka, base + dA0);
        GLDS16(aS1 + ka, base + dA1);
    };
    auto WRITEB = [&](int buf) {
        short* d = lds + buf * BUFS + rB + bOff;
#pragma unroll
        for (int j = 0; j < 4; j++) {
            const int col = c4 + j;
            const int colS = col ^ ((col >> 3) & 7);
            s16x4 o;
            o[0] = f2bf(bq[0][j]); o[1] = f2bf(bq[1][j]);
            o[2] = f2bf(bq[2][j]); o[3] = f2bf(bq[3][j]);
            *(s16x4*)(d + colS * 8) = o;
        }
    };

    // frag reads: A [4 kg][256 rows][8]; B [mat][4 kg][128 colS][8]
    const int aO = kg * 2048 + (wr * 64 + ln) * 8;

    f32x4 acc[2][4][4] = {};            // [mat][m][nf]
    const int nt = K / 32;

    // ---- prologue ---- (issue order B(0), A(0), B(1), A(1))
    LOADB(0);
    __builtin_amdgcn_sched_barrier(0);
    STGA(0, 0);
    __builtin_amdgcn_sched_barrier(0);
    WRITEB(0);                       // auto-wait retires B(0)
    __builtin_amdgcn_sched_barrier(0);
    LOADB(1);
    __builtin_amdgcn_sched_barrier(0);
    asm volatile("s_waitcnt lgkmcnt(0)" ::: "memory");
    STGA(1, 1);
    __builtin_amdgcn_sched_barrier(0);

    int cur = 0;
    for (int ks = 0; ks < nt; ks++) {
        if (ks + 1 < nt) asm volatile("s_waitcnt vmcnt(6)" ::: "memory");
        else             asm volatile("s_waitcnt vmcnt(0)" ::: "memory");
        __builtin_amdgcn_s_barrier();
        __builtin_amdgcn_sched_barrier(0);   // frag reads must not hoist

        const short* base = lds + cur * BUFS;
        s16x8 af[4];
#pragma unroll
        for (int m = 0; m < 4; m++)
            af[m] = *(const s16x8*)(base + aO + m * 128);
        s16x8 bf[2][4];
#pragma unroll
        for (int nf = 0; nf < 4; nf++) {
            const int col  = wc * 64 + nf * 16 + ln;
            const int colS = col ^ ((col >> 3) & 7);
#pragma unroll
            for (int mat = 0; mat < 2; mat++)
                bf[mat][nf] = *(const s16x8*)(base + 8192 + mat * 4096 +
                                              kg * 1024 + colS * 8);
        }

        // MFMA + next-step B cvt/write in one region (separate pipes co-issue)
#pragma unroll
        for (int nf = 0; nf < 4; nf++)
#pragma unroll
            for (int m = 0; m < 4; m++)
#pragma unroll
                for (int mat = 0; mat < 2; mat++)
                    acc[mat][m][nf] = __builtin_amdgcn_mfma_f32_16x16x32_bf16(
                        af[m], bf[mat][nf], acc[mat][m][nf], 0, 0, 0);

        if (ks + 1 < nt) WRITEB(cur ^ 1);

        __builtin_amdgcn_sched_barrier(0);   // WRITEB consumes bq before reload
        if (ks + 2 < nt) LOADB(ks + 2);      // issue before barrier drain
        __builtin_amdgcn_sched_barrier(0);
        asm volatile("s_waitcnt lgkmcnt(0)" ::: "memory");
        __builtin_amdgcn_s_barrier();

        if (ks + 2 < nt) {
            STGA(cur, ks + 2);               // buf[cur] free after barrier
            __builtin_amdgcn_sched_barrier(0);
        }
        cur ^= 1;
    }

    // Epilogue: silu(g)*u, chunk [N/8][oRpad][8]; store-guard row < rlim.
    // C/D: col = lane&15, row = (lane>>4)*4 + j  [m89-verified]
#pragma unroll
    for (int m = 0; m < 4; m++) {
#pragma unroll
        for (int nf = 0; nf < 4; nf++) {
            const int row = m0 + wr * 64 + m * 16 + kg * 4;
            const int col = n0 + wc * 64 + nf * 16 + ln;
            if (row < S.rlim) {
#pragma unroll
                for (int j = 0; j < 4; j++) {
                    float gv = acc[0][m][nf][j];
                    float uv = acc[1][m][nf][j];
                    float v = gv / (1.f + __expf(-gv)) * uv;
                    S.Out[(size_t)g * S.oStride + (size_t)(col >> 3) * (S.oRpad * 8) +
                          (size_t)(row + j) * 8 + (col & 7)] = f2bf(v);
                }
            }
        }
    }
}

// ---------------- GLDS bf16-B GEMM, BM=64 x BN=256 (down projections) -------
// r17-proven: BN=256 halves A re-reads; (256,3), 40 KB LDS.
__device__ void gemm_down_dev(const GSegB& S, int bid)
{
    constexpr int BUFS = 10240;         // shorts: A 2048 + B 8192 (20 KB)
    __shared__ short lds[2 * BUFS];

    const int cpx = S.nblocks >> 3;
    const int lid = (bid & 7) * cpx + (bid >> 3);
    const int mb  = lid % S.Mb;
    const int t1  = lid / S.Mb;
    const int nb  = t1 % S.Nb;
    const int g   = t1 / S.Nb;
    const int m0 = mb * 64, n0 = nb * 256;
    if (S.cnt != nullptr && m0 >= S.cnt[g]) return;

    const int tid = threadIdx.x, lane = tid & 63, w = tid >> 6;
    const int wr = w >> 1, wc = w & 1, ln = lane & 15, kg = lane >> 4;
    const int N = S.N, K = S.K;

    const short* Ag = S.A  + (size_t)g * S.aStride + (size_t)m0 * 8;
    const short* Bg = S.B0 + (size_t)g * S.bStride + (size_t)n0 * 8;

    const size_t aR8 = (size_t)S.aRpad * 8;
    const size_t n8  = (size_t)N * 8;

    const short* aS = Ag + (size_t)(tid >> 6) * aR8 + (size_t)(tid & 63) * 8;
    const short* bS = Bg + (size_t)tid * 8;
    const int dA = w * 512;

    auto STG = [&](int buf, int ks) {
        const size_t ka = (size_t)ks * 4 * aR8;
        const size_t kb = (size_t)ks * 4 * n8;
        short* base = lds + buf * BUFS;
        GLDS16(aS + ka, base + dA);
#pragma unroll
        for (int i = 0; i < 4; i++)
            GLDS16(bS + kb + (size_t)i * n8, base + 2048 + i * 2048 + w * 512);
    };

    const int aO = kg * 512 + (wr * 32 + ln) * 8;              // A [4kg][64][8]
    const int bBase = 2048 + kg * 2048 + (wc * 128 + ln) * 8;  // B [4kg][256][8]

    f32x4 acc[2][8] = {};
    const int nt = K / 32;
    STG(0, 0); STG(1, 1);
    int cur = 0;
    for (int ks = 0; ks < nt; ks++) {
        if (ks + 1 < nt) asm volatile("s_waitcnt vmcnt(5)" ::: "memory");
        else             asm volatile("s_waitcnt vmcnt(0)" ::: "memory");
        __builtin_amdgcn_s_barrier();
        __builtin_amdgcn_sched_barrier(0);

        const short* base = lds + cur * BUFS;
        s16x8 af[2];
        af[0] = *(const s16x8*)(base + aO);
        af[1] = *(const s16x8*)(base + aO + 128);
        s16x8 bf[8];
#pragma unroll
        for (int nf = 0; nf < 8; nf++)
            bf[nf] = *(const s16x8*)(base + bBase + nf * 128);

#pragma unroll
        for (int nf = 0; nf < 8; nf++)
#pragma unroll
            for (int m = 0; m < 2; m++)
                acc[m][nf] = __builtin_amdgcn_mfma_f32_16x16x32_bf16(
                    af[m], bf[nf], acc[m][nf], 0, 0, 0);

        __builtin_amdgcn_sched_barrier(0);
        __builtin_amdgcn_s_barrier();
        if (ks + 2 < nt) STG(cur, ks + 2);
        cur ^= 1;
    }

    // Epilogue (canonical [row][N])
#pragma unroll
    for (int m = 0; m < 2; m++) {
#pragma unroll
        for (int nf = 0; nf < 8; nf++) {
            const int row = m0 + wr * 32 + m * 16 + kg * 4;
            const int col = n0 + wc * 128 + nf * 16 + ln;
#pragma unroll
            for (int j = 0; j < 4; j++)
                S.Out[(size_t)g * S.oStride + (size_t)(row + j) * N + col] =
                    f2bf(acc[m][nf][j]);
        }
    }
}

// ---------------- K2: gate+up fused (BM=256, 512 thr) + wd/swd conversion ---
// (512,2): 2 waves/SIMD -> 256-reg budget; kernel needs ~220 (acc 128 +
// staging/frags ~90). Higher min-waves would spill acc (r4 signature).
__global__ __launch_bounds__(512, 2) void gateup_kernel(GSegF s0, GSegF s1,
                                                        WSeg w0, WSeg w1)
{
    int bid = blockIdx.x;
    if (bid < s0.nblocks) { gemm_fused256_dev(s0, bid); return; }
    bid -= s0.nblocks;
    if (bid < s1.nblocks) { gemm_fused256_dev(s1, bid); return; }
    bid -= s1.nblocks;
    if (bid < w0.nblocks) { wchunk_dev(w0, bid); return; }
    wchunk_dev(w1, bid - w0.nblocks);
}

// ---------------- K3: down GEMMs (BN=256, 3 blocks/CU) ----------------------
__global__ __launch_bounds__(256, 3) void down_kernel(GSegB s0, GSegB s1)
{
    int bid = blockIdx.x;
    if (bid < s0.nblocks) { gemm_down_dev(s0, bid); return; }
    gemm_down_dev(s1, bid - s0.nblocks);
}

// ---------------- Combine: out = x + shared + sum_k w_k * expert_row --------
__global__ __launch_bounds__(256) void combine_kernel(
    const float* __restrict__ x, const short* __restrict__ shout,
    const short* __restrict__ eout, const int* __restrict__ dst,
    const float* __restrict__ wgt, float* __restrict__ out)
{
    const int t = blockIdx.x;
    const int d = threadIdx.x * 4;
    size_t o = (size_t)t * DIM + d;
    float4 xv = *(const float4*)(x + o);
    s16x4 sv = *(const s16x4*)(shout + o);
    float r0 = xv.x + bf2f(sv[0]);
    float r1 = xv.y + bf2f(sv[1]);
    float r2 = xv.z + bf2f(sv[2]);
    float r3 = xv.w + bf2f(sv[3]);
#pragma unroll
    for (int k = 0; k < 2; k++) {
        int di = dst[t * 2 + k];
        if (di >= 0) {
            float wv = wgt[t * 2 + k];
            s16x4 ev = *(const s16x4*)(eout + (size_t)di * DIM + d);
            r0 += wv * bf2f(ev[0]);
            r1 += wv * bf2f(ev[1]);
            r2 += wv * bf2f(ev[2]);
            r3 += wv * bf2f(ev[3]);
        }
    }
    float4 rv = {r0, r1, r2, r3};
    *(float4*)(out + o) = rv;
}

extern "C" void kernel_launch(void* const* d_in, const int* in_sizes, int n_in,
                              void* d_out, int out_size, void* d_ws, size_t ws_size,
                              hipStream_t stream)
{
    const float* x   = (const float*)d_in[0];
    const float* rw  = (const float*)d_in[1];
    const float* rb  = (const float*)d_in[2];
    const float* wg  = (const float*)d_in[3];
    const float* wu  = (const float*)d_in[4];
    const float* wd  = (const float*)d_in[5];
    const float* swg = (const float*)d_in[6];
    const float* swu = (const float*)d_in[7];
    const float* swd = (const float*)d_in[8];
    float* out = (float*)d_out;

    char* wp = (char*)d_ws;
    auto alloc = [&](size_t b) { char* p = wp; wp += (b + 255) & ~(size_t)255; return p; };
    int*   idx_flat = (int*)alloc((size_t)NK * 4);
    float* vals     = (float*)alloc((size_t)NK * 4);
    int*   dst      = (int*)alloc((size_t)NK * 4);
    float* wgt      = (float*)alloc((size_t)NK * 4);
    int*   cnt      = (int*)alloc(64);
    short* xb       = (short*)alloc((size_t)TOKENS * DIM * 2);          // chunk
    // ex: +128 rows slack (BM=256 block-1 A-reads overrun rows 384..511)
    short* ex       = (short*)alloc(((size_t)NEXP * RPAD + 128) * DIM * 2);
    short* acte     = (short*)alloc((size_t)NEXP * RPAD * FDIM * 2);    // chunk
    short* acts     = (short*)alloc((size_t)TOKENS * FDIM * 2);         // chunk
    short* eout     = (short*)alloc((size_t)NEXP * RPAD * DIM * 2);     // canonical
    short* shout    = (short*)alloc((size_t)TOKENS * DIM * 2);          // canonical
    short* wdC      = (short*)alloc((size_t)NEXP * DIM * FDIM * 2);     // chunk
    short* swdC     = (short*)alloc((size_t)DIM * FDIM * 2);            // chunk

    // K1: router + xconv -> scan (critical path for scatter)
    rx_kernel<<<TOKENS / 16 + TOKENS / 2, 256, 0, stream>>>(x, rw, rb,
                                                            idx_flat, vals, xb);
    scan_kernel<<<1, 64, 0, stream>>>(idx_flat, vals, dst, wgt, cnt);

    // K-mid: scatter only
    scatter_kernel<<<NK / 2, 256, 0, stream>>>(x, dst, idx_flat, ex);

    // K2: gate+up fused (BM=256) + wd/swd conversion riding
    GSegF segGE = {ex, (long)RPAD * DIM, RPAD, wg, wu, (long)DIM * FDIM,
                   acte, (long)RPAD * FDIM, RPAD, cnt, 2, 11, FDIM, DIM,
                   RPAD, 2 * 11 * NEXP};
    GSegF segGS = {xb, 0L, TOKENS, swg, swu, 0L,
                   acts, 0L, TOKENS, nullptr, 8, 11, FDIM, DIM,
                   TOKENS, 8 * 11};
    WSeg Wd  = {wd,  wdC,  FDIM, DIM, NEXP, NEXP * (FDIM / 8)};   // 2816
    WSeg Wsd = {swd, swdC, FDIM, DIM, 1,    FDIM / 8};            // 176
    gateup_kernel<<<segGE.nblocks + segGS.nblocks + Wd.nblocks + Wsd.nblocks,
                    512, 0, stream>>>(segGE, segGS, Wd, Wsd);

    // K3: down GEMMs (GLDS bf16 weights, BM=64 x BN=256)
    GSegB segDE = {acte, (long)RPAD * FDIM, RPAD, wdC, (long)DIM * FDIM,
                   eout, (long)RPAD * DIM, cnt, 6, 4, DIM, FDIM, 6 * 4 * NEXP};
    GSegB segDS = {acts, 0L, TOKENS, swdC, 0L,
                   shout, 0L, nullptr, 32, 4, DIM, FDIM, 32 * 4};
    down_kernel<<<segDE.nblocks + segDS.nblocks, 256, 0, stream>>>(segDE, segDS);

    combine_kernel<<<TOKENS, 256, 0, stream>>>(x, shout, eout, dst, wgt, out);
}

// Round 19
// 224.058 us; speedup vs baseline: 1.0561x; 1.0561x over previous
//
#include <hip/hip_runtime.h>
#include <hip/hip_bf16.h>

#define TOKENS 2048
#define DIM    1024
#define FDIM   1408
#define NEXP   16
#define NK     (TOKENS * 2)
#define CAP    320
#define RPAD   384          // padded rows per expert (3 x 128 / 6 x 64)

typedef __attribute__((ext_vector_type(4))) float f32x4;
typedef __attribute__((ext_vector_type(2))) float f32x2;
typedef __attribute__((ext_vector_type(8))) short s16x8;
typedef __attribute__((ext_vector_type(4))) short s16x4;

__device__ __forceinline__ short f2bf(float f) {
    unsigned int u = __float_as_uint(f);
    u += 0x7FFFu + ((u >> 16) & 1u);   // RNE
    return (short)(u >> 16);
}
__device__ __forceinline__ float bf2f(short s) {
    return __uint_as_float(((unsigned int)(unsigned short)s) << 16);
}
// Pair convert (RNE, same bits as f2bf for finite inputs).
__device__ __forceinline__ unsigned int f2bf_pk(float lo, float hi) {
    union { __hip_bfloat162 h; unsigned int u; } c;
    c.h = __float22bfloat162_rn(make_float2(lo, hi));
    return c.u;
}

#define GLDS16(gp, lp) __builtin_amdgcn_global_load_lds(                     \
    (const __attribute__((address_space(1))) unsigned int*)(gp),             \
    (__attribute__((address_space(3))) unsigned int*)(lp), 16, 0, 0)

// ---------------- arg structs ----------------
struct GSegF {                       // fused-conversion GEMM (fp32 B)
    const short* A; long aStride; int aRpad;
    const float* B0; const float* B1; long bStride;
    short* Out; long oStride; int oRpad;
    const int* cnt; int Mb, Nb, N, K, nblocks;
};
struct GSegB {                       // GLDS bf16-B GEMM (BM=64, BN=256)
    const short* A; long aStride; int aRpad;
    const short* B0; long bStride;
    short* Out; long oStride;
    const int* cnt; int Mb, Nb, N, K, nblocks;
};
struct WSeg { const float* in; short* out; int K, N, mats, nblocks; };

// ------- Weight chunk-reorder: fp32 [K][N] -> bf16 [K/8][N][8] --------------
// Slab scheme (r6/r10): block = one 8-row k-slab; thread owns 2 adjacent cols.
__device__ void wchunk_dev(const WSeg& W, int bid)
{
    const int spm = W.K >> 3;
    const int mat = bid / spm, s = bid % spm;
    const float* in  = W.in  + (size_t)mat * W.K * W.N + (size_t)s * 8 * W.N;
    short* out = W.out + (size_t)mat * W.K * W.N + (size_t)s * W.N * 8;
    const int t = threadIdx.x;
    const int iters = (W.N + 511) >> 9;
    for (int it = 0; it < iters; it++) {
        const int n = it * 512 + 2 * t;
        if (n >= W.N) break;
        const float* src = in + n;
        s16x8 o0, o1;
#pragma unroll
        for (int j = 0; j < 8; j++) {
            float2 v = *(const float2*)(src + (size_t)j * W.N);
            o0[j] = f2bf(v.x);
            o1[j] = f2bf(v.y);
        }
        *(s16x8*)(out + (size_t)n * 8)     = o0;
        *(s16x8*)(out + (size_t)n * 8 + 8) = o1;
    }
}

// -------- Router device: logits -> softmax -> top2 -> renormalize -----------
__device__ void router_dev(const float* __restrict__ x, const float* __restrict__ rw,
                           const float* __restrict__ rb, int* __restrict__ idx_flat,
                           float* __restrict__ vals_flat, int bid)
{
    __shared__ float lg[16][17];
    const int t  = threadIdx.x;
    const int tl = t >> 4;
    const int e  = t & 15;
    const int token = bid * 16 + tl;
    const float* xr = x + (size_t)token * DIM;

    float acc = 0.f;
    for (int d4 = 0; d4 < DIM / 4; d4++) {
        float4 xv = *(const float4*)(xr + d4 * 4);
        acc += xv.x * rw[(d4 * 4 + 0) * NEXP + e];
        acc += xv.y * rw[(d4 * 4 + 1) * NEXP + e];
        acc += xv.z * rw[(d4 * 4 + 2) * NEXP + e];
        acc += xv.w * rw[(d4 * 4 + 3) * NEXP + e];
    }
    lg[tl][e] = acc + rb[e];
    __syncthreads();

    if (t < 16) {
        float l[16];
#pragma unroll
        for (int j = 0; j < 16; j++) l[j] = lg[t][j];
        float m = l[0];
#pragma unroll
        for (int j = 1; j < 16; j++) m = fmaxf(m, l[j]);
        float p[16], den = 0.f;
#pragma unroll
        for (int j = 0; j < 16; j++) { p[j] = __expf(l[j] - m); den += p[j]; }
        int i1 = -1; float b1 = -1e30f;
#pragma unroll
        for (int j = 0; j < 16; j++) if (p[j] > b1) { b1 = p[j]; i1 = j; }
        int i2 = -1; float b2 = -1e30f;
#pragma unroll
        for (int j = 0; j < 16; j++) if (j != i1 && p[j] > b2) { b2 = p[j]; i2 = j; }
        float v1 = b1 / den, v2 = b2 / den;
        float s = v1 + v2 + 1e-9f;
        int tok = bid * 16 + t;
        idx_flat[tok * 2 + 0] = i1;
        idx_flat[tok * 2 + 1] = i2;
        vals_flat[tok * 2 + 0] = v1 / s;
        vals_flat[tok * 2 + 1] = v2 / s;
    }
}

// -------- xconv device: x -> bf16 chunk [DIM/8][TOKENS][8]; 2 tokens/block --
__device__ void xconv_dev(const float* __restrict__ x, short* __restrict__ xb, int bid)
{
    const int token = bid * 2 + (threadIdx.x >> 7);
    const int c = threadIdx.x & 127;
    const float* src = x + (size_t)token * DIM + c * 8;
    float4 v0 = *(const float4*)(src);
    float4 v1 = *(const float4*)(src + 4);
    s16x8 o;
    o[0] = f2bf(v0.x); o[1] = f2bf(v0.y); o[2] = f2bf(v0.z); o[3] = f2bf(v0.w);
    o[4] = f2bf(v1.x); o[5] = f2bf(v1.y); o[6] = f2bf(v1.z); o[7] = f2bf(v1.w);
    *(s16x8*)(xb + (size_t)c * (TOKENS * 8) + (size_t)token * 8) = o;
}

// ---- K1: router + xconv (xconv has no scan dependency -> off critical path)
__global__ __launch_bounds__(256) void rx_kernel(
    const float* __restrict__ x, const float* __restrict__ rw,
    const float* __restrict__ rb, int* __restrict__ idx_flat,
    float* __restrict__ vals, short* __restrict__ xb)
{
    int bid = blockIdx.x;
    if (bid < TOKENS / 16) { router_dev(x, rw, rb, idx_flat, vals, bid); return; }
    xconv_dev(x, xb, bid - TOKENS / 16);
}

// ------------- Sequential position scan (1 wave, ballot-based) --------------
__global__ void scan_kernel(const int* __restrict__ idx_flat,
                            const float* __restrict__ vals,
                            int* __restrict__ dst, float* __restrict__ wgt,
                            int* __restrict__ cnt)
{
    const int lane = threadIdx.x;   // 64 threads
    int base[16];
#pragma unroll
    for (int e = 0; e < 16; e++) base[e] = 0;

    for (int c = 0; c < NK / 64; c++) {
        int i = c * 64 + lane;
        int e = idx_flat[i];
        unsigned long long m[16];
#pragma unroll
        for (int ee = 0; ee < 16; ee++) m[ee] = __ballot(e == ee);
        unsigned long long mym = 0ULL; int myb = 0;
#pragma unroll
        for (int ee = 0; ee < 16; ee++) {
            bool sel = (e == ee);
            mym = sel ? m[ee] : mym;
            myb = sel ? base[ee] : myb;
        }
        int pos = myb + (int)__popcll(mym & ((1ULL << lane) - 1ULL));
        bool within = pos < CAP;
        dst[i] = within ? (e * RPAD + pos) : -1;
        wgt[i] = within ? vals[i] : 0.f;
#pragma unroll
        for (int ee = 0; ee < 16; ee++) base[ee] += (int)__popcll(m[ee]);
    }
    if (lane < 16) cnt[lane] = base[lane] < CAP ? base[lane] : CAP;
}

// ---- Scatter: token into expert buffer chunk [K/8][RPAD][8]; 2/block -------
__global__ __launch_bounds__(256) void scatter_kernel(
    const float* __restrict__ x, const int* __restrict__ dst,
    const int* __restrict__ idx_flat, short* __restrict__ ex)
{
    const int i = blockIdx.x * 2 + (threadIdx.x >> 7);
    const int d0 = dst[i];
    if (d0 < 0) return;
    const int e = idx_flat[i];
    const int pos = d0 - e * RPAD;
    const int token = i >> 1;
    const int c = threadIdx.x & 127;
    const float* src = x + (size_t)token * DIM + c * 8;
    float4 v0 = *(const float4*)(src);
    float4 v1 = *(const float4*)(src + 4);
    s16x8 o;
    o[0] = f2bf(v0.x); o[1] = f2bf(v0.y); o[2] = f2bf(v0.z); o[3] = f2bf(v0.w);
    o[4] = f2bf(v1.x); o[5] = f2bf(v1.y); o[6] = f2bf(v1.z); o[7] = f2bf(v1.w);
    *(s16x8*)(ex + (size_t)e * (DIM * RPAD) + (size_t)c * (RPAD * 8) +
              (size_t)pos * 8) = o;
}

// ---------------- Fused-conversion GEMM (gate+up), BM=128 -------------------
// r10/r15/r17 champion kernel. A: bf16 chunk via global_load_lds.
// B: fp32 [K][N] staged global->reg->pk-cvt->ds_write (8 loads/thread).
// B LDS cols XOR-swizzled colS = col ^ ((col>>3)&7) both sides (r8: 7.43M->0).
// vmcnt ledger: top of iter ks outstanding = A(ks)2 + B(ks+1)8 + A(ks+1)2
// = 12 -> vmcnt(10) retires A(ks). WRITEB's bq auto-waited by compiler.
// Eight structural variants (r7-r18) all land 128-145 us; this is the best.
template <int NMAT>
__device__ void gemm_fused_dev(const GSegF& S, int bid)
{
    constexpr int BUFS = 4096 * (1 + NMAT);     // shorts per pipeline buffer
    __shared__ short lds[2 * BUFS];

    const int cpx = S.nblocks >> 3;             // XCD swizzle, m fastest
    const int lid = (bid & 7) * cpx + (bid >> 3);
    const int mb  = lid % S.Mb;
    const int t1  = lid / S.Mb;
    const int nb  = t1 % S.Nb;
    const int g   = t1 / S.Nb;
    const int m0 = mb * 128, n0 = nb * 128;
    if (S.cnt != nullptr && m0 >= S.cnt[g]) return;

    const int tid = threadIdx.x, lane = tid & 63, w = tid >> 6;
    const int wr = w >> 1, wc = w & 1, ln = lane & 15, kg = lane >> 4;
    const int N = S.N, K = S.K;

    const short* Ag  = S.A  + (size_t)g * S.aStride + (size_t)m0 * 8;
    const float* Bg0 = S.B0 + (size_t)g * S.bStride + n0;
    const float* Bg1 = nullptr;
    if constexpr (NMAT == 2) Bg1 = S.B1 + (size_t)g * S.bStride + n0;

    const size_t aR8 = (size_t)S.aRpad * 8;

    const int srow = tid & 127, sslab = tid >> 7;
    const short* aS0 = Ag + sslab * aR8 + srow * 8;
    const short* aS1 = Ag + (2 + sslab) * aR8 + srow * 8;
    const int dA0 = w * 512, dA1 = 2048 + w * 512;

    const float* bSrc;
    int rB, cW;
    if constexpr (NMAT == 2) {
        const int c4 = tid & 31, gq = (tid >> 5) & 3, mat = tid >> 7;
        bSrc = (mat ? Bg1 : Bg0) + (size_t)gq * 8 * N + c4 * 4;
        rB = 4096 + mat * 4096 + gq * 1024;
        cW = c4;
    } else {
        const int c2 = tid & 63, gq = tid >> 6;
        bSrc = Bg0 + (size_t)gq * 8 * N + c2 * 2;
        rB = 4096 + gq * 1024;
        cW = c2;
    }

    f32x4 bq[8];
    f32x2 bd[8];

    auto LOADB = [&](int ks) {
        const float* p = bSrc + (size_t)ks * 32 * N;
        if constexpr (NMAT == 2) {
#pragma unroll
            for (int j = 0; j < 8; j++) bq[j] = *(const f32x4*)(p + (size_t)j * N);
        } else {
#pragma unroll
            for (int j = 0; j < 8; j++) bd[j] = *(const f32x2*)(p + (size_t)j * N);
        }
    };
    auto STGA = [&](int buf, int ks) {
        const size_t ka = (size_t)ks * 4 * aR8;
        short* base = lds + buf * BUFS;
        GLDS16(aS0 + ka, base + dA0);
        GLDS16(aS1 + ka, base + dA1);
    };
    auto WRITEB = [&](int buf) {
        short* d = lds + buf * BUFS + rB;
        if constexpr (NMAT == 2) {
#pragma unroll
            for (int j = 0; j < 4; j++) {
                const int colS = (cW * 4 + j) ^ ((cW >> 1) & 7);
                uint4 o;
                o.x = f2bf_pk(bq[0][j], bq[1][j]);
                o.y = f2bf_pk(bq[2][j], bq[3][j]);
                o.z = f2bf_pk(bq[4][j], bq[5][j]);
                o.w = f2bf_pk(bq[6][j], bq[7][j]);
                *(uint4*)(d + colS * 8) = o;
            }
        } else {
#pragma unroll
            for (int j = 0; j < 2; j++) {
                const int colS = (cW * 2 + j) ^ ((cW >> 2) & 7);
                uint4 o;
                o.x = f2bf_pk(bd[0][j], bd[1][j]);
                o.y = f2bf_pk(bd[2][j], bd[3][j]);
                o.z = f2bf_pk(bd[4][j], bd[5][j]);
                o.w = f2bf_pk(bd[6][j], bd[7][j]);
                *(uint4*)(d + colS * 8) = o;
            }
        }
    };

    const int aO = kg * 1024 + (wr * 64 + ln) * 8;

    f32x4 acc[NMAT][4][4] = {};
    const int nt = K / 32;

    // ---- prologue ---- (issue order B(0), A(0), B(1), A(1) matches ledger)
    LOADB(0);
    __builtin_amdgcn_sched_barrier(0);
    STGA(0, 0);
    __builtin_amdgcn_sched_barrier(0);
    WRITEB(0);                       // auto-wait retires B(0)
    __builtin_amdgcn_sched_barrier(0);
    LOADB(1);
    __builtin_amdgcn_sched_barrier(0);
    asm volatile("s_waitcnt lgkmcnt(0)" ::: "memory");
    STGA(1, 1);
    __builtin_amdgcn_sched_barrier(0);

    int cur = 0;
    for (int ks = 0; ks < nt; ks++) {
        if (ks + 1 < nt) asm volatile("s_waitcnt vmcnt(10)" ::: "memory");
        else             asm volatile("s_waitcnt vmcnt(0)"  ::: "memory");
        __builtin_amdgcn_s_barrier();
        __builtin_amdgcn_sched_barrier(0);   // frag reads must not hoist

        const short* base = lds + cur * BUFS;
        s16x8 af[4];
#pragma unroll
        for (int m = 0; m < 4; m++)
            af[m] = *(const s16x8*)(base + aO + m * 128);
        s16x8 bf[NMAT][4];
#pragma unroll
        for (int nf = 0; nf < 4; nf++) {
            const int col  = wc * 64 + nf * 16 + ln;
            const int colS = col ^ ((col >> 3) & 7);
#pragma unroll
            for (int mat = 0; mat < NMAT; mat++)
                bf[mat][nf] = *(const s16x8*)(base + 4096 + mat * 4096 +
                                              kg * 1024 + colS * 8);
        }

        // MFMA + next-step B cvt/write in one region (separate pipes co-issue)
#pragma unroll
        for (int nf = 0; nf < 4; nf++)
#pragma unroll
            for (int m = 0; m < 4; m++)
#pragma unroll
                for (int mat = 0; mat < NMAT; mat++)
                    acc[mat][m][nf] = __builtin_amdgcn_mfma_f32_16x16x32_bf16(
                        af[m], bf[mat][nf], acc[mat][m][nf], 0, 0, 0);

        if (ks + 1 < nt) WRITEB(cur ^ 1);

        __builtin_amdgcn_sched_barrier(0);   // WRITEB consumes bq before reload
        if (ks + 2 < nt) LOADB(ks + 2);      // issue before barrier drain
        __builtin_amdgcn_sched_barrier(0);
        asm volatile("s_waitcnt lgkmcnt(0)" ::: "memory");
        __builtin_amdgcn_s_barrier();

        if (ks + 2 < nt) {
            STGA(cur, ks + 2);               // buf[cur] free after barrier
            __builtin_amdgcn_sched_barrier(0);
        }
        cur ^= 1;
    }

    // Epilogue. C/D: col = lane&15, row = (lane>>4)*4 + j  [m89-verified]
#pragma unroll
    for (int m = 0; m < 4; m++) {
#pragma unroll
        for (int nf = 0; nf < 4; nf++) {
            const int row = m0 + wr * 64 + m * 16 + kg * 4;
            const int col = n0 + wc * 64 + nf * 16 + ln;
#pragma unroll
            for (int j = 0; j < 4; j++) {
                if constexpr (NMAT == 2) {
                    float gv = acc[0][m][nf][j];
                    float uv = acc[1][m][nf][j];
                    float v = gv / (1.f + __expf(-gv)) * uv;
                    S.Out[(size_t)g * S.oStride + (size_t)(col >> 3) * (S.oRpad * 8) +
                          (size_t)(row + j) * 8 + (col & 7)] = f2bf(v);
                } else {
                    S.Out[(size_t)g * S.oStride + (size_t)(row + j) * N + col] =
                        f2bf(acc[0][m][nf][j]);
                }
            }
        }
    }
}

// ---------------- GLDS bf16-B GEMM, BM=64 x BN=256 (down projections) -------
// r17-proven: BN=256 halves A re-reads (down was A-refetch-bound). Tile
// 64x256, 4 waves (2x2, each 32x128); (256,3); 40 KB LDS; vmcnt(5) ledger.
__device__ void gemm_down_dev(const GSegB& S, int bid)
{
    constexpr int BUFS = 10240;         // shorts: A 2048 + B 8192 (20 KB)
    __shared__ short lds[2 * BUFS];

    const int cpx = S.nblocks >> 3;
    const int lid = (bid & 7) * cpx + (bid >> 3);
    const int mb  = lid % S.Mb;
    const int t1  = lid / S.Mb;
    const int nb  = t1 % S.Nb;
    const int g   = t1 / S.Nb;
    const int m0 = mb * 64, n0 = nb * 256;
    if (S.cnt != nullptr && m0 >= S.cnt[g]) return;

    const int tid = threadIdx.x, lane = tid & 63, w = tid >> 6;
    const int wr = w >> 1, wc = w & 1, ln = lane & 15, kg = lane >> 4;
    const int N = S.N, K = S.K;

    const short* Ag = S.A  + (size_t)g * S.aStride + (size_t)m0 * 8;
    const short* Bg = S.B0 + (size_t)g * S.bStride + (size_t)n0 * 8;

    const size_t aR8 = (size_t)S.aRpad * 8;
    const size_t n8  = (size_t)N * 8;

    const short* aS = Ag + (size_t)(tid >> 6) * aR8 + (size_t)(tid & 63) * 8;
    const short* bS = Bg + (size_t)tid * 8;
    const int dA = w * 512;

    auto STG = [&](int buf, int ks) {
        const size_t ka = (size_t)ks * 4 * aR8;
        const size_t kb = (size_t)ks * 4 * n8;
        short* base = lds + buf * BUFS;
        GLDS16(aS + ka, base + dA);
#pragma unroll
        for (int i = 0; i < 4; i++)
            GLDS16(bS + kb + (size_t)i * n8, base + 2048 + i * 2048 + w * 512);
    };

    const int aO = kg * 512 + (wr * 32 + ln) * 8;              // A [4kg][64][8]
    const int bBase = 2048 + kg * 2048 + (wc * 128 + ln) * 8;  // B [4kg][256][8]

    f32x4 acc[2][8] = {};
    const int nt = K / 32;
    STG(0, 0); STG(1, 1);
    int cur = 0;
    for (int ks = 0; ks < nt; ks++) {
        if (ks + 1 < nt) asm volatile("s_waitcnt vmcnt(5)" ::: "memory");
        else             asm volatile("s_waitcnt vmcnt(0)" ::: "memory");
        __builtin_amdgcn_s_barrier();
        __builtin_amdgcn_sched_barrier(0);

        const short* base = lds + cur * BUFS;
        s16x8 af[2];
        af[0] = *(const s16x8*)(base + aO);
        af[1] = *(const s16x8*)(base + aO + 128);
        s16x8 bf[8];
#pragma unroll
        for (int nf = 0; nf < 8; nf++)
            bf[nf] = *(const s16x8*)(base + bBase + nf * 128);

#pragma unroll
        for (int nf = 0; nf < 8; nf++)
#pragma unroll
            for (int m = 0; m < 2; m++)
                acc[m][nf] = __builtin_amdgcn_mfma_f32_16x16x32_bf16(
                    af[m], bf[nf], acc[m][nf], 0, 0, 0);

        __builtin_amdgcn_sched_barrier(0);
        __builtin_amdgcn_s_barrier();
        if (ks + 2 < nt) STG(cur, ks + 2);
        cur ^= 1;
    }

    // Epilogue (canonical [row][N])
#pragma unroll
    for (int m = 0; m < 2; m++) {
#pragma unroll
        for (int nf = 0; nf < 8; nf++) {
            const int row = m0 + wr * 32 + m * 16 + kg * 4;
            const int col = n0 + wc * 128 + nf * 16 + ln;
#pragma unroll
            for (int j = 0; j < 4; j++)
                S.Out[(size_t)g * S.oStride + (size_t)(row + j) * N + col] =
                    f2bf(acc[m][nf][j]);
        }
    }
}

// ---------------- K2: gate+up fused GEMMs + down-weight conversion ----------
// NOTE: min-waves MUST stay at 2 here (256 regs/thread budget; acc alone is
// 128). 3+ spills accumulators (r4: WRITE_SIZE 575 MB, 285 us dispatch).
__global__ __launch_bounds__(256, 2) void gateup_kernel(GSegF s0, GSegF s1,
                                                        WSeg w0, WSeg w1)
{
    int bid = blockIdx.x;
    if (bid < s0.nblocks) { gemm_fused_dev<2>(s0, bid); return; }
    bid -= s0.nblocks;
    if (bid < s1.nblocks) { gemm_fused_dev<2>(s1, bid); return; }
    bid -= s1.nblocks;
    if (bid < w0.nblocks) { wchunk_dev(w0, bid); return; }
    wchunk_dev(w1, bid - w0.nblocks);
}

// ---------------- K3: down GEMMs (BN=256, 3 blocks/CU) ----------------------
__global__ __launch_bounds__(256, 3) void down_kernel(GSegB s0, GSegB s1)
{
    int bid = blockIdx.x;
    if (bid < s0.nblocks) { gemm_down_dev(s0, bid); return; }
    gemm_down_dev(s1, bid - s0.nblocks);
}

// ---------------- Combine: out = x + shared + sum_k w_k * expert_row --------
__global__ __launch_bounds__(256) void combine_kernel(
    const float* __restrict__ x, const short* __restrict__ shout,
    const short* __restrict__ eout, const int* __restrict__ dst,
    const float* __restrict__ wgt, float* __restrict__ out)
{
    const int t = blockIdx.x;
    const int d = threadIdx.x * 4;
    size_t o = (size_t)t * DIM + d;
    float4 xv = *(const float4*)(x + o);
    s16x4 sv = *(const s16x4*)(shout + o);
    float r0 = xv.x + bf2f(sv[0]);
    float r1 = xv.y + bf2f(sv[1]);
    float r2 = xv.z + bf2f(sv[2]);
    float r3 = xv.w + bf2f(sv[3]);
#pragma unroll
    for (int k = 0; k < 2; k++) {
        int di = dst[t * 2 + k];
        if (di >= 0) {
            float wv = wgt[t * 2 + k];
            s16x4 ev = *(const s16x4*)(eout + (size_t)di * DIM + d);
            r0 += wv * bf2f(ev[0]);
            r1 += wv * bf2f(ev[1]);
            r2 += wv * bf2f(ev[2]);
            r3 += wv * bf2f(ev[3]);
        }
    }
    float4 rv = {r0, r1, r2, r3};
    *(float4*)(out + o) = rv;
}

extern "C" void kernel_launch(void* const* d_in, const int* in_sizes, int n_in,
                              void* d_out, int out_size, void* d_ws, size_t ws_size,
                              hipStream_t stream)
{
    const float* x   = (const float*)d_in[0];
    const float* rw  = (const float*)d_in[1];
    const float* rb  = (const float*)d_in[2];
    const float* wg  = (const float*)d_in[3];
    const float* wu  = (const float*)d_in[4];
    const float* wd  = (const float*)d_in[5];
    const float* swg = (const float*)d_in[6];
    const float* swu = (const float*)d_in[7];
    const float* swd = (const float*)d_in[8];
    float* out = (float*)d_out;

    char* wp = (char*)d_ws;
    auto alloc = [&](size_t b) { char* p = wp; wp += (b + 255) & ~(size_t)255; return p; };
    int*   idx_flat = (int*)alloc((size_t)NK * 4);
    float* vals     = (float*)alloc((size_t)NK * 4);
    int*   dst      = (int*)alloc((size_t)NK * 4);
    float* wgt      = (float*)alloc((size_t)NK * 4);
    int*   cnt      = (int*)alloc(64);
    short* xb       = (short*)alloc((size_t)TOKENS * DIM * 2);          // chunk
    short* ex       = (short*)alloc((size_t)NEXP * RPAD * DIM * 2);     // chunk
    short* acte     = (short*)alloc((size_t)NEXP * RPAD * FDIM * 2);    // chunk
    short* acts     = (short*)alloc((size_t)TOKENS * FDIM * 2);         // chunk
    short* eout     = (short*)alloc((size_t)NEXP * RPAD * DIM * 2);     // canonical
    short* shout    = (short*)alloc((size_t)TOKENS * DIM * 2);          // canonical
    short* wdC      = (short*)alloc((size_t)NEXP * DIM * FDIM * 2);     // chunk
    short* swdC     = (short*)alloc((size_t)DIM * FDIM * 2);            // chunk

    // K1: router + xconv -> scan (critical path for scatter)
    rx_kernel<<<TOKENS / 16 + TOKENS / 2, 256, 0, stream>>>(x, rw, rb,
                                                            idx_flat, vals, xb);
    scan_kernel<<<1, 64, 0, stream>>>(idx_flat, vals, dst, wgt, cnt);

    // K-mid: scatter only
    scatter_kernel<<<NK / 2, 256, 0, stream>>>(x, dst, idx_flat, ex);

    // K2: gate+up fused GEMMs + wd/swd conversion riding the idle HBM
    GSegF segGE = {ex, (long)RPAD * DIM, RPAD, wg, wu, (long)DIM * FDIM,
                   acte, (long)RPAD * FDIM, RPAD, cnt, 3, 11, FDIM, DIM, 3 * 11 * NEXP};
    GSegF segGS = {xb, 0L, TOKENS, swg, swu, 0L,
                   acts, 0L, TOKENS, nullptr, 16, 11, FDIM, DIM, 16 * 11};
    WSeg Wd  = {wd,  wdC,  FDIM, DIM, NEXP, NEXP * (FDIM / 8)};   // 2816
    WSeg Wsd = {swd, swdC, FDIM, DIM, 1,    FDIM / 8};            // 176
    gateup_kernel<<<segGE.nblocks + segGS.nblocks + Wd.nblocks + Wsd.nblocks,
                    256, 0, stream>>>(segGE, segGS, Wd, Wsd);

    // K3: down GEMMs (GLDS bf16 weights, BM=64 x BN=256)
    GSegB segDE = {acte, (long)RPAD * FDIM, RPAD, wdC, (long)DIM * FDIM,
                   eout, (long)RPAD * DIM, cnt, 6, 4, DIM, FDIM, 6 * 4 * NEXP};
    GSegB segDS = {acts, 0L, TOKENS, swdC, 0L,
                   shout, 0L, nullptr, 32, 4, DIM, FDIM, 32 * 4};
    down_kernel<<<segDE.nblocks + segDS.nblocks, 256, 0, stream>>>(segDE, segDS);

    combine_kernel<<<TOKENS, 256, 0, stream>>>(x, shout, eout, dst, wgt, out);
}